// Round 3
// baseline (104816.187 us; speedup 1.0000x reference)
//
#include <hip/hip_runtime.h>

#define Bq 32
#define Sq 2048
#define Iq 128
#define Hq 512
#define Oq 128
#define NWG 256
#define NT 256
#define SSTRIDE 260              // dword stride per LDS row (256 + 4 pad)
#define SHBYTES (128 * SSTRIDE * 4)  // 133120 B dynamic LDS (<= 160 KiB)

__device__ __forceinline__ float sigmoidf_(float v) {
    return 1.0f / (1.0f + __expf(-v));
}

// Coherent-at-LLC data access, NO cache-maintenance fences.
__device__ __forceinline__ float ld_coh(const float* p) {
    return __hip_atomic_load(p, __ATOMIC_RELAXED, __HIP_MEMORY_SCOPE_AGENT);
}
__device__ __forceinline__ void st_coh(float* p, float v) {
    __hip_atomic_store(p, v, __ATOMIC_RELAXED, __HIP_MEMORY_SCOPE_AGENT);
}

// Flag barrier, one LLC hop: block i's thread 0 stores epoch to flag[i]
// (after vmcnt drain => all the block's coherent stores are at the LLC);
// EVERY block's thread j polls flag[j] (NWG==NT). No central publish hop.
// Flags monotone, no resets. Flags at bar[2*i], within zeroed 1024-int region.
__device__ __forceinline__ void gridbar(int* bar, int target) {
    __syncthreads();
    if (threadIdx.x == 0) {
        asm volatile("s_waitcnt vmcnt(0) lgkmcnt(0)" ::: "memory");
        __hip_atomic_store(bar + (blockIdx.x << 1), target, __ATOMIC_RELAXED,
                           __HIP_MEMORY_SCOPE_AGENT);
    }
    while (__hip_atomic_load(bar + (threadIdx.x << 1), __ATOMIC_RELAXED,
                             __HIP_MEMORY_SCOPE_AGENT) < target) {
        __builtin_amdgcn_s_sleep(1);
    }
    __syncthreads();
}

// Stage one 32x512 buffer (row stride 512) into LDS rows [0,64) of dst:
// rows 0-31 = cols [0,256), rows 32-63 = cols [256,512). Coalesced: thread
// tid loads column tid of every row. No internal syncs; caller syncs after.
__device__ __forceinline__ void stage2(float* dst, const float* g) {
    const int tid = threadIdx.x;
    float va[32], vb[32];
#pragma unroll
    for (int u = 0; u < 32; ++u) va[u] = ld_coh(g + u * 512 + tid);
#pragma unroll
    for (int u = 0; u < 32; ++u) vb[u] = ld_coh(g + u * 512 + 256 + tid);
#pragma unroll
    for (int u = 0; u < 32; ++u) dst[u * SSTRIDE + tid] = va[u];
#pragma unroll
    for (int u = 0; u < 32; ++u) dst[(32 + u) * SSTRIDE + tid] = vb[u];
}

// Stage TWO 32x512 buffers (g0 -> rows 0-63, g1 -> rows 64-127) with a
// pipelined 3-buffer schedule: ~1.5 latency exposures instead of 4.
__device__ __forceinline__ void stage4(float* dst, const float* g0,
                                       const float* g1) {
    const int tid = threadIdx.x;
    float va[32], vb[32], vc[32];
#pragma unroll
    for (int u = 0; u < 32; ++u) va[u] = ld_coh(g0 + u * 512 + tid);
#pragma unroll
    for (int u = 0; u < 32; ++u) vb[u] = ld_coh(g0 + u * 512 + 256 + tid);
#pragma unroll
    for (int u = 0; u < 32; ++u) vc[u] = ld_coh(g1 + u * 512 + tid);
#pragma unroll
    for (int u = 0; u < 32; ++u) dst[u * SSTRIDE + tid] = va[u];
#pragma unroll
    for (int u = 0; u < 32; ++u) va[u] = ld_coh(g1 + u * 512 + 256 + tid);
#pragma unroll
    for (int u = 0; u < 32; ++u) dst[(32 + u) * SSTRIDE + tid] = vb[u];
#pragma unroll
    for (int u = 0; u < 32; ++u) dst[(64 + u) * SSTRIDE + tid] = vc[u];
#pragma unroll
    for (int u = 0; u < 32; ++u) dst[(96 + u) * SSTRIDE + tid] = va[u];
}

// Stage 32 x 128 chunk of IMMUTABLE input x (plain cached loads), coalesced.
__device__ __forceinline__ void stage128p(float* sst, const float* g,
                                          long rowStride) {
    const int tid = threadIdx.x;
    const int k4 = tid & 31, bb = tid >> 5;
#pragma unroll
    for (int u = 0; u < 4; ++u) {
        int b = bb + (u << 3);
        float4 v = *(const float4*)(g + (long)b * rowStride + (k4 << 2));
        *(float4*)(sst + b * SSTRIDE + (k4 << 2)) = v;
    }
}

// K=512 dot: weight row (cached, wave-broadcast) vs staged rows {b, 32+b}.
__device__ __forceinline__ float dot512(const float* sb,
                                        const float* __restrict__ Wrow,
                                        int b) {
    const float* s0 = sb + b * SSTRIDE;
    const float* s1 = sb + (32 + b) * SSTRIDE;
    float a0 = 0.f, a1 = 0.f, a2 = 0.f, a3 = 0.f;
#pragma unroll 8
    for (int k = 0; k < 256; k += 4) {
        float4 w = *(const float4*)(Wrow + k);
        float4 h = *(const float4*)(s0 + k);
        a0 = fmaf(w.x, h.x, a0);
        a1 = fmaf(w.y, h.y, a1);
        a2 = fmaf(w.z, h.z, a2);
        a3 = fmaf(w.w, h.w, a3);
    }
#pragma unroll 8
    for (int k = 0; k < 256; k += 4) {
        float4 w = *(const float4*)(Wrow + 256 + k);
        float4 h = *(const float4*)(s1 + k);
        a0 = fmaf(w.x, h.x, a0);
        a1 = fmaf(w.y, h.y, a1);
        a2 = fmaf(w.z, h.z, a2);
        a3 = fmaf(w.w, h.w, a3);
    }
    return (a0 + a1) + (a2 + a3);
}

// K-length dot (K=128 for x-side), rows b only.
__device__ __forceinline__ float dotC(const float* sst,
                                      const float* __restrict__ Wrow, int b,
                                      int K) {
    const float* s = sst + b * SSTRIDE;
    float a0 = 0.f, a1 = 0.f, a2 = 0.f, a3 = 0.f;
#pragma unroll 8
    for (int k = 0; k < K; k += 4) {
        float4 w = *(const float4*)(Wrow + k);
        float4 h = *(const float4*)(s + k);
        a0 = fmaf(w.x, h.x, a0);
        a1 = fmaf(w.y, h.y, a1);
        a2 = fmaf(w.z, h.z, a2);
        a3 = fmaf(w.w, h.w, a3);
    }
    return (a0 + a1) + (a2 + a3);
}

__global__ void bar_init(int* bar) {
    for (int i = threadIdx.x; i < 1024; i += 256) bar[i] = 0;
}

// 2-tick-per-timestep pipelined schedule, rebalanced:
//   E(t): wg 0-127  : stage h0; A1(t) z0/rh0 (2 dots)
//         wg 0-63   : + C2(t-1) xg1 (2 dots, same staged h0)
//         wg 64-79  : + stage h1; Y(t-2) (2 dots)     [max 4 dots/thread]
//         wg 128-255: stage h0+h1; C1(t-1) z1/rh1 (4 dots, fused hzr1)
//   O(t): wg 0-63   : stage rh0; B1(t) h0 update
//         wg 64-127 : stage rh1; D1(t-1) h1 update
//         wg 128-223: stage x; X(t+1) xzr0/xg0[par]
__global__ __launch_bounds__(NT, 1) void gru_fused(
    const float* __restrict__ x, const float* __restrict__ h0in,
    const float* __restrict__ Wx0, const float* __restrict__ Wh0,
    const float* __restrict__ bh0, const float* __restrict__ Wx1,
    const float* __restrict__ Wh1, const float* __restrict__ bh1,
    const float* __restrict__ Why, const float* __restrict__ bhy,
    float* __restrict__ out, float* __restrict__ ws) {
    extern __shared__ float sst[];
    const int wg = blockIdx.x;
    const int tid = threadIdx.x;
    int* bar = (int*)(ws + 180224);
    int ep = 0;

    // workspace layout (floats) — all cross-block data, coherent access only
    float* h0 = ws;              // [b*512+j]
    float* h1 = ws + 16384;
    float* xzr0 = ws + 32768;    // [b*1024+jj]
    float* xg0 = ws + 65536;     // 2 x [b*512+j], parity t&1
    float* z0 = ws + 98304;
    float* rh0 = ws + 114688;
    float* z1 = ws + 131072;
    float* rh1 = ws + 147456;
    float* xg1 = ws + 163840;

    // ---- pre-tick: init h0/h1; X(0) into xzr0 + xg0[0] ----
    if (wg < 86) {
        for (int i = wg * NT + tid; i < 2 * Bq * Hq; i += 86 * NT) {
            int b = i >> 10, l = (i >> 9) & 1, j = i & 511;
            st_coh((l ? h1 : h0) + b * Hq + j, h0in[i]);
        }
    } else if (wg >= 128 && wg < 224) {
        stage128p(sst, x, (long)Sq * Iq);  // x_0
        __syncthreads();
        int base = (wg - 128) * 512;
#pragma unroll
        for (int c = 0; c < 2; ++c) {
            int lid = base + c * NT + tid;
            int b = lid & 31, jj = lid >> 5;  // jj in [0,1536)
            float d = dotC(sst, Wx0 + jj * Iq, b, Iq);
            if (jj < 1024)
                st_coh(xzr0 + b * 1024 + jj, d);
            else
                st_coh(xg0 + b * Hq + (jj - 1024), d);  // parity 0
        }
    }
    gridbar(bar, ++ep);

    for (int t = 0; t <= Sq; ++t) {
        // ======== E tick ========
        if (wg < 128) {
            int lid = wg * NT + tid;
            int b = lid & 31, j = lid >> 5;  // j in [0,1024)
            bool doA = (t < Sq);
            bool doC2 = (wg < 64) && (t >= 1);
            bool hasY = (wg >= 64 && wg < 80);
            if (hasY)
                stage4(sst, h0, h1);
            else
                stage2(sst, h0);
            // prefetch tail operands while stage loads drain
            float xv = doA ? ld_coh(xzr0 + b * 1024 + j) : 0.f;
            float bj = doA ? bh0[j] : 0.f;
            int lidY = (wg - 64) * NT + tid;
            int bY = lidY & 31, oY = lidY >> 5;
            bool doY = hasY && (t >= 2);
            float by = doY ? bhy[oY] : 0.f;
            __syncthreads();
            if (doA) {
                float accA = dot512(sst, Wh0 + j * Hq, b);
                float s = sigmoidf_(xv + accA + bj);
                if (j < Hq) {
                    st_coh(z0 + b * Hq + j, s);
                } else {
                    int jc = j - Hq;
                    float hval = (jc < 256)
                                     ? sst[b * SSTRIDE + jc]
                                     : sst[(32 + b) * SSTRIDE + (jc - 256)];
                    st_coh(rh0 + b * Hq + jc, s * hval);
                }
            }
            if (doC2) {
                float accC = dot512(sst, Wx1 + (2 * Hq + j) * Hq, b);
                st_coh(xg1 + b * Hq + j, accC);
            }
            if (doY) {
                float accY = dot512(sst + 64 * SSTRIDE, Why + oY * Hq, bY);
                out[((size_t)bY * Sq + (t - 2)) * Oq + oY] = accY + by;
            }
        } else {
            // C1(t-1): fused z1/r1 (h0 and h1 sides), wg 128-255
            int lid = (wg - 128) * NT + tid;
            int b = lid & 31, j = lid >> 5;  // j in [0,1024)
            bool doC1 = (t >= 1);
            stage4(sst, h0, h1);
            float bj = doC1 ? bh1[j] : 0.f;
            __syncthreads();
            if (doC1) {
                float acc1 = dot512(sst, Wx1 + j * Hq, b);
                float acc2 = dot512(sst + 64 * SSTRIDE, Wh1 + j * Hq, b);
                float s = sigmoidf_(acc1 + acc2 + bj);
                if (j < Hq) {
                    st_coh(z1 + b * Hq + j, s);
                } else {
                    int jc = j - Hq;
                    float hval = (jc < 256)
                                     ? sst[(64 + b) * SSTRIDE + jc]
                                     : sst[(96 + b) * SSTRIDE + (jc - 256)];
                    st_coh(rh1 + b * Hq + jc, s * hval);
                }
            }
        }
        gridbar(bar, ++ep);

        // ======== O tick ========
        if (wg < 64) {
            // B1(t): h0 update
            if (t < Sq) {
                int lid = wg * NT + tid;
                int b = lid & 31, j = lid >> 5;  // [0,512)
                stage2(sst, rh0);
                float xgv = ld_coh(xg0 + (t & 1) * 16384 + b * Hq + j);
                float zz = ld_coh(z0 + b * Hq + j);
                float hold = ld_coh(h0 + b * Hq + j);
                float bj = bh0[2 * Hq + j];
                __syncthreads();
                float acc = dot512(sst, Wh0 + (2 * Hq + j) * Hq, b);
                float g = tanhf(xgv + acc + bj);
                st_coh(h0 + b * Hq + j, zz * hold + (1.f - zz) * g);
            }
        } else if (wg < 128) {
            // D1(t-1): h1 update
            if (t >= 1) {
                int lid = (wg - 64) * NT + tid;
                int b = lid & 31, j = lid >> 5;
                stage2(sst, rh1);
                float xgv = ld_coh(xg1 + b * Hq + j);
                float zz = ld_coh(z1 + b * Hq + j);
                float hold = ld_coh(h1 + b * Hq + j);
                float bj = bh1[2 * Hq + j];
                __syncthreads();
                float acc = dot512(sst, Wh1 + (2 * Hq + j) * Hq, b);
                float g = tanhf(xgv + acc + bj);
                st_coh(h1 + b * Hq + j, zz * hold + (1.f - zz) * g);
            }
        } else if (wg < 224) {
            // X(t+1): xzr0 and xg0[par] for next step
            if (t + 1 < Sq) {
                stage128p(sst, x + (long)(t + 1) * Iq, (long)Sq * Iq);
                __syncthreads();
                int base = (wg - 128) * 512;
                int par = (t + 1) & 1;
#pragma unroll
                for (int c = 0; c < 2; ++c) {
                    int lid = base + c * NT + tid;
                    int b = lid & 31, jj = lid >> 5;
                    float d = dotC(sst, Wx0 + jj * Iq, b, Iq);
                    if (jj < 1024)
                        st_coh(xzr0 + b * 1024 + jj, d);
                    else
                        st_coh(xg0 + par * 16384 + b * Hq + (jj - 1024), d);
                }
            }
        }
        gridbar(bar, ++ep);
    }

    // ---- final tick: hidden state + Y(Sq-1) ----
    if (wg < 128) {
        int i = wg * NT + tid;  // 32768 = B*L*H
        int b = i >> 10, l = (i >> 9) & 1, j = i & 511;
        out[(size_t)Bq * Sq * Oq + i] = ld_coh((l ? h1 : h0) + b * Hq + j);
    } else if (wg >= 240) {
        int lid = (wg - 240) * NT + tid;  // 4096 = B*O
        int b = lid & 31, o = lid >> 5;
        stage2(sst, h1);
        __syncthreads();
        float acc = dot512(sst, Why + o * Hq, b);
        out[((size_t)b * Sq + (Sq - 1)) * Oq + o] = acc + bhy[o];
    }
}

extern "C" void kernel_launch(void* const* d_in, const int* in_sizes, int n_in,
                              void* d_out, int out_size, void* d_ws,
                              size_t ws_size, hipStream_t stream) {
    const float* x = (const float*)d_in[0];
    const float* h0in = (const float*)d_in[1];
    const float* Wx0 = (const float*)d_in[2];
    const float* Wh0 = (const float*)d_in[3];
    const float* bh0 = (const float*)d_in[4];
    const float* Wx1 = (const float*)d_in[5];
    const float* Wh1 = (const float*)d_in[6];
    const float* bh1 = (const float*)d_in[7];
    const float* Why = (const float*)d_in[8];
    const float* bhy = (const float*)d_in[9];
    float* out = (float*)d_out;
    float* ws = (float*)d_ws;
    int* bar = (int*)(ws + 180224);

    bar_init<<<1, 256, 0, stream>>>(bar);
    gru_fused<<<dim3(NWG), dim3(NT), SHBYTES, stream>>>(
        x, h0in, Wx0, Wh0, bh0, Wx1, Wh1, bh1, Why, bhy, out, ws);
}